// Round 1
// baseline (341.278 us; speedup 1.0000x reference)
//
#include <hip/hip_runtime.h>

// Trilinear sampler: im [B,H,W,D,C] f32, coords [B,N,3] f32 (y,x,z), out [B,N,C] f32.
// B=2, H=W=D=128, C=2, N=H*W*D. Reference zero-pads im by 1 on each spatial side
// and offsets coords by +1; we emulate the pad with validity-masked weights so
// all 8 corner loads are unconditional (branch-free, max outstanding loads).

constexpr int Bc = 2, Hc = 128, Wc = 128, Dc = 128, Cc = 2;
constexpr int Npts = Hc * Wc * Dc;                       // 2,097,152 points per batch
constexpr long long TOTPTS = (long long)Bc * Npts;       // 4,194,304
constexpr int PTS_PER_THREAD = 4;
constexpr int NTHREADS = (int)(TOTPTS / PTS_PER_THREAD); // 1,048,576
constexpr int BLOCK = 256;

__global__ __launch_bounds__(BLOCK)
void TrilinearSampler_34059090658011_kernel(const float* __restrict__ im,
                                            const float* __restrict__ coords,
                                            float* __restrict__ out) {
    const int t = blockIdx.x * BLOCK + threadIdx.x;      // one thread = 4 points

    // coords for 4 points = 12 floats = 3 aligned float4 loads (coalesced)
    const float4* __restrict__ c4 = reinterpret_cast<const float4*>(coords);
    const float4 ca = c4[3 * t + 0];
    const float4 cb = c4[3 * t + 1];
    const float4 cc = c4[3 * t + 2];

    const int p0 = t * PTS_PER_THREAD;                   // first point index (global)
    const int b  = p0 >> 21;                             // / Npts (2^21); 4 points never straddle batches
    const float2* __restrict__ imb =
        reinterpret_cast<const float2*>(im) + (size_t)b * (size_t)Npts; // per-(y,x,z) float2 (C=2)

    // per-point (y,x,z) triples from the three float4s
    const float ys[4] = {ca.x, ca.w, cb.z, cc.y};
    const float xs[4] = {ca.y, cb.x, cb.w, cc.z};
    const float zs[4] = {ca.z, cb.y, cc.x, cc.w};

    float res[8];

#pragma unroll
    for (int i = 0; i < 4; ++i) {
        // padded-space coordinates (reference adds +1 for the zero border)
        const float x = xs[i] + 1.0f;
        const float y = ys[i] + 1.0f;
        const float z = zs[i] + 1.0f;

        int x0 = (int)floorf(x);
        int y0 = (int)floorf(y);
        int z0 = (int)floorf(z);
        // reference: x1 = clip(x0+1, 0, W+1); x0 = clip(x0, 0, W+1)  (padded dims = 130)
        int x1 = ::min(x0 + 1, Wc + 1);
        int y1 = ::min(y0 + 1, Hc + 1);
        int z1 = ::min(z0 + 1, Dc + 1);
        x0 = ::min(::max(x0, 0), Wc + 1);
        y0 = ::min(::max(y0, 0), Hc + 1);
        z0 = ::min(::max(z0, 0), Dc + 1);

        const float dx = (float)x1 - x;
        const float dy = (float)y1 - y;
        const float dz = (float)z1 - z;

        // map padded index -> original index; pad cells contribute 0 via masked weight
        int ix0 = x0 - 1, ix1 = x1 - 1;
        int iy0 = y0 - 1, iy1 = y1 - 1;
        int iz0 = z0 - 1, iz1 = z1 - 1;
        const float fx0 = ((unsigned)ix0 < (unsigned)Wc) ? 1.0f : 0.0f;
        const float fx1 = ((unsigned)ix1 < (unsigned)Wc) ? 1.0f : 0.0f;
        const float fy0 = ((unsigned)iy0 < (unsigned)Hc) ? 1.0f : 0.0f;
        const float fy1 = ((unsigned)iy1 < (unsigned)Hc) ? 1.0f : 0.0f;
        const float fz0 = ((unsigned)iz0 < (unsigned)Dc) ? 1.0f : 0.0f;
        const float fz1 = ((unsigned)iz1 < (unsigned)Dc) ? 1.0f : 0.0f;
        // clamp so masked-out loads still read a safe address
        ix0 = ::min(::max(ix0, 0), Wc - 1); ix1 = ::min(::max(ix1, 0), Wc - 1);
        iy0 = ::min(::max(iy0, 0), Hc - 1); iy1 = ::min(::max(iy1, 0), Hc - 1);
        iz0 = ::min(::max(iz0, 0), Dc - 1); iz1 = ::min(::max(iz1, 0), Dc - 1);

        // corner weights in the (y,x) plane; z handled as two planes
        const float w00 = dx * dy * fx0 * fy0;                     // (y0, x0)
        const float w01 = dx * (1.0f - dy) * fx0 * fy1;            // (y1, x0)
        const float w10 = (1.0f - dx) * dy * fx1 * fy0;            // (y0, x1)
        const float w11 = (1.0f - dx) * (1.0f - dy) * fx1 * fy1;   // (y1, x1)
        const float wz0 = dz * fz0;
        const float wz1 = (1.0f - dz) * fz1;

        const int r00 = (iy0 * Wc + ix0) * Dc;
        const int r01 = (iy1 * Wc + ix0) * Dc;
        const int r10 = (iy0 * Wc + ix1) * Dc;
        const int r11 = (iy1 * Wc + ix1) * Dc;

        // 8 unconditional float2 gathers (both channels in one 8B load)
        const float2 g000 = imb[r00 + iz0];
        const float2 g001 = imb[r00 + iz1];
        const float2 g010 = imb[r01 + iz0];
        const float2 g011 = imb[r01 + iz1];
        const float2 g100 = imb[r10 + iz0];
        const float2 g101 = imb[r10 + iz1];
        const float2 g110 = imb[r11 + iz0];
        const float2 g111 = imb[r11 + iz1];

        const float a0x = w00 * g000.x + w01 * g010.x + w10 * g100.x + w11 * g110.x;
        const float a0y = w00 * g000.y + w01 * g010.y + w10 * g100.y + w11 * g110.y;
        const float a1x = w00 * g001.x + w01 * g011.x + w10 * g101.x + w11 * g111.x;
        const float a1y = w00 * g001.y + w01 * g011.y + w10 * g101.y + w11 * g111.y;

        res[2 * i + 0] = wz0 * a0x + wz1 * a1x;
        res[2 * i + 1] = wz0 * a0y + wz1 * a1y;
    }

    // 4 points * C=2 = 8 floats = two aligned float4 stores (coalesced)
    float4* __restrict__ o4 = reinterpret_cast<float4*>(out);
    o4[2 * t + 0] = make_float4(res[0], res[1], res[2], res[3]);
    o4[2 * t + 1] = make_float4(res[4], res[5], res[6], res[7]);
}

extern "C" void kernel_launch(void* const* d_in, const int* in_sizes, int n_in,
                              void* d_out, int out_size, void* d_ws, size_t ws_size,
                              hipStream_t stream) {
    const float* im     = (const float*)d_in[0];
    const float* coords = (const float*)d_in[1];
    float* out          = (float*)d_out;

    dim3 grid(NTHREADS / BLOCK);
    dim3 block(BLOCK);
    TrilinearSampler_34059090658011_kernel<<<grid, block, 0, stream>>>(im, coords, out);
}